// Round 11
// baseline (166.492 us; speedup 1.0000x reference)
//
#include <hip/hip_runtime.h>
#include <math.h>

// SelectiveSSMBlock: B=2, L=2048, D=1024, N=16, R=64, fp32.
// R11: R10 minus the standalone k_delta — the delta GEMM is fused into scan1
// (per-thread dtw weights in VGPRs, xz rows via the scalar path scan1 already
// uses), which writes del once for scan3. 6 nodes.

#define LOG2E 1.44269504088896340736f
typedef float v2f __attribute__((ext_vector_type(2)));

__device__ __forceinline__ float fexp2(float v){
#if defined(__has_builtin)
#if __has_builtin(__builtin_amdgcn_exp2f)
  return __builtin_amdgcn_exp2f(v);
#else
  return exp2f(v);
#endif
#else
  return exp2f(v);
#endif
}

__device__ __forceinline__ float fsoftplus(float v){
  return fmaxf(v, 0.f) + __logf(1.f + __expf(-fabsf(v)));
}

// ---------------- prep: w2T[k][96] = xpw[c][k]*sig(te[k]). Grid 96.
__global__ __launch_bounds__(256) void k_prep(const float* __restrict__ xpw,
                                              const float* __restrict__ te,
                                              float* __restrict__ w2T){
  __shared__ float sm[32 * 33];
  const int bid = blockIdx.x, t = threadIdx.x;
  const int lane = t & 31, srow = t >> 5;
  const int kt = bid / 3, ct = bid - kt * 3;
#pragma unroll
  for (int r = 0; r < 4; r++){
    const int cr = srow * 4 + r;
    sm[cr * 33 + lane] = xpw[(size_t)(ct * 32 + cr) * 1024 + kt * 32 + lane];
  }
  __syncthreads();
#pragma unroll
  for (int r = 0; r < 4; r++){
    const int kr = srow * 4 + r;
    const int kg = kt * 32 + kr;
    const float s = 1.f / (1.f + __expf(-te[kg]));
    w2T[(size_t)kg * 96 + ct * 32 + lane] = sm[lane * 33 + kr] * s;
  }
}

// ---------------- xz partial GEMM, K-split 8 (KC=128). Grid (16,3,8). [R7/R10 body]
__global__ __launch_bounds__(256) void k_xz(const float* __restrict__ x,
                                            const float* __restrict__ w2T,
                                            float* __restrict__ xzp){
  __shared__ float xT[32 * 257];
  const int t = threadIdx.x;
  const int row0 = blockIdx.x * 256;
  const int c0 = blockIdx.y * 32;
  const int kbase = blockIdx.z * 128;
  v2f acc[16];
#pragma unroll
  for (int c = 0; c < 16; c++) acc[c] = (v2f){0.f, 0.f};
  const int kq = t & 7, rsub = t >> 3;
  for (int kt = 0; kt < 4; ++kt){
    const int k0 = kbase + kt * 32;
    __syncthreads();
#pragma unroll
    for (int p = 0; p < 8; p++){
      const int r = p * 32 + rsub;
      const float4 v = *reinterpret_cast<const float4*>(&x[(size_t)(row0 + r) * 1024 + k0 + kq * 4]);
      xT[(kq * 4 + 0) * 257 + r] = v.x;
      xT[(kq * 4 + 1) * 257 + r] = v.y;
      xT[(kq * 4 + 2) * 257 + r] = v.z;
      xT[(kq * 4 + 3) * 257 + r] = v.w;
    }
    __syncthreads();
#pragma unroll 4
    for (int kk = 0; kk < 32; ++kk){
      const float xv = xT[kk * 257 + t];
      const v2f xv2 = {xv, xv};
      const v2f* wr = reinterpret_cast<const v2f*>(&w2T[(size_t)(k0 + kk) * 96 + c0]); // uniform sequential -> s_load
#pragma unroll
      for (int c = 0; c < 16; c++) acc[c] = acc[c] + xv2 * wr[c];
    }
  }
  float4* o = reinterpret_cast<float4*>(xzp + ((size_t)blockIdx.z * 4096 + row0 + t) * 96 + c0);
  const float4* av = reinterpret_cast<const float4*>(acc);
#pragma unroll
  for (int q = 0; q < 8; q++) o[q] = av[q];
}

// ---------------- reduce 8 partials -> xz. Grid 384.
__global__ __launch_bounds__(256) void k_reduce(const float4* __restrict__ p,
                                                float4* __restrict__ xz){
  const int i = blockIdx.x * 256 + threadIdx.x;
  float4 r = p[i];
#pragma unroll
  for (int s = 1; s < 8; s++){
    const float4 a = p[(size_t)s * 98304 + i];
    r.x += a.x; r.y += a.y; r.z += a.z; r.w += a.w;
  }
  xz[i] = r;
}

// ---------------- scan1 (+fused delta GEMM): C=64, len=32. Grid (64,4,2).
// delta weights per-thread in VGPRs (R10 k_delta mechanism); writes del for scan3.
__global__ __launch_bounds__(256) void k_scan1(const float* __restrict__ x,
                                               const float* __restrict__ xz,
                                               const float* __restrict__ dtw,
                                               const float* __restrict__ dtb,
                                               const float* __restrict__ alog,
                                               const float* __restrict__ te,
                                               float* __restrict__ del,
                                               float* __restrict__ S,
                                               float* __restrict__ P){
  const int t = threadIdx.x;
  const int chunk = blockIdx.x, dgrp = blockIdx.y, b = blockIdx.z;
  const int d = dgrp * 256 + t;
  const int l0 = chunk * 32;
  v2f wv[32];
  {
    const v2f* wp = reinterpret_cast<const v2f*>(dtw + (size_t)d * 64);  // per-thread contiguous
#pragma unroll
    for (int k2 = 0; k2 < 32; k2++) wv[k2] = wp[k2];
  }
  const float dtbv = dtb[d];
  float a2[16];
  {
    const float4* ap = reinterpret_cast<const float4*>(alog + (size_t)d * 16);
#pragma unroll
    for (int q = 0; q < 4; q++){
      const float4 v = ap[q];
      a2[q*4+0] = -__expf(v.x) * LOG2E; a2[q*4+1] = -__expf(v.y) * LOG2E;
      a2[q*4+2] = -__expf(v.z) * LOG2E; a2[q*4+3] = -__expf(v.w) * LOG2E;
    }
  }
  bool uni = true;
#pragma unroll
  for (int n = 1; n < 16; n++) uni = uni && (a2[n] == a2[0]);
  const float sgv = 1.f / (1.f + __expf(-te[d]));
  const size_t xidx0 = (size_t)(b * 2048 + l0) * 1024 + d;
  const float* xzb = xz + (size_t)(b * 2048 + l0) * 96;
  const size_t base = ((size_t)((b * 64 + chunk) * 1024 + d)) * 16;
  if (uni){
    const float a2u = a2[0];
    v2f h2[8];
#pragma unroll
    for (int q = 0; q < 8; q++) h2[q] = (v2f){0.f, 0.f};
    float sumd = 0.f;
    for (int ph = 0; ph < 2; ++ph){
      const size_t xidx = xidx0 + (size_t)ph * 16 * 1024;
      float dl[16], du[16];
#pragma unroll
      for (int li = 0; li < 16; ++li){
        v2f acc = {dtbv, 0.f};
        const v2f* dp = reinterpret_cast<const v2f*>(xzb + (ph * 16 + li) * 96);  // uniform -> s_load
#pragma unroll
        for (int k2 = 0; k2 < 32; k2++) acc = acc + dp[k2] * wv[k2];
        dl[li] = fsoftplus(acc.x + acc.y);
        del[xidx + (size_t)li * 1024] = dl[li];
        du[li] = dl[li] * x[xidx + (size_t)li * 1024] * sgv;
      }
#pragma unroll 4
      for (int li = 0; li < 16; ++li){
        sumd += dl[li];
        const float tt = fexp2(dl[li] * a2u);
        const v2f tt2 = {tt, tt}, du2 = {du[li], du[li]};
        const v2f* brow = reinterpret_cast<const v2f*>(xzb + (ph * 16 + li) * 96 + 64);
#pragma unroll
        for (int q = 0; q < 8; q++) h2[q] = h2[q] * tt2 + brow[q] * du2;
      }
    }
    const float Ppu = fexp2(a2u * sumd);
    const float4* hv = reinterpret_cast<const float4*>(h2);
#pragma unroll
    for (int q = 0; q < 4; q++)
      *reinterpret_cast<float4*>(&S[base + q * 4]) = hv[q];
    const float4 pv = {Ppu, Ppu, Ppu, Ppu};
#pragma unroll
    for (int q = 0; q < 4; q++)
      *reinterpret_cast<float4*>(&P[base + q * 4]) = pv;
  } else {
    float h[16], Pp[16];
#pragma unroll
    for (int n = 0; n < 16; n++){ h[n] = 0.f; Pp[n] = 1.f; }
    for (int li = 0; li < 32; ++li){
      v2f accd = {dtbv, 0.f};
      const v2f* dp = reinterpret_cast<const v2f*>(xzb + li * 96);
#pragma unroll
      for (int k2 = 0; k2 < 32; k2++) accd = accd + dp[k2] * wv[k2];
      const float dv = fsoftplus(accd.x + accd.y);
      del[xidx0 + (size_t)li * 1024] = dv;
      const float duv = dv * x[xidx0 + (size_t)li * 1024] * sgv;
      const float* brow = xzb + li * 96 + 64;
#pragma unroll
      for (int n = 0; n < 16; n++){
        const float tt = fexp2(dv * a2[n]);
        h[n] = fmaf(tt, h[n], duv * brow[n]);
        Pp[n] *= tt;
      }
    }
#pragma unroll
    for (int q = 0; q < 4; q++){
      float4 v; v.x = h[q*4]; v.y = h[q*4+1]; v.z = h[q*4+2]; v.w = h[q*4+3];
      *reinterpret_cast<float4*>(&S[base + q * 4]) = v;
      float4 u; u.x = Pp[q*4]; u.y = Pp[q*4+1]; u.z = Pp[q*4+2]; u.w = Pp[q*4+3];
      *reinterpret_cast<float4*>(&P[base + q * 4]) = u;
    }
  }
}

// ---------------- scan2: single-walk segmented combine, C=64. Grid 1024 x 256.
__global__ __launch_bounds__(256) void k_scan2(const float* __restrict__ S,
                                               const float* __restrict__ P,
                                               float* __restrict__ H){
  __shared__ float ls[256], lp[256];
  const int t = threadIdx.x;
  const int dn = t & 31, seg = t >> 5;
  const int n = dn & 15, dloc = dn >> 4;
  const int bid = blockIdx.x;
  const int b = bid >> 9, dpair = bid & 511;
  const int d = dpair * 2 + dloc;
  const size_t sbase = ((size_t)(b * 64) * 1024 + d) * 16 + n;
  float Sv[8], Pv[8];
  float s = 0.f, p = 1.f;
#pragma unroll
  for (int i = 0; i < 8; i++){
    const size_t idx = sbase + (size_t)(seg * 8 + i) * 16384;
    Sv[i] = S[idx]; Pv[i] = P[idx];
    s = fmaf(Pv[i], s, Sv[i]);
    p *= Pv[i];
  }
  ls[t] = s; lp[t] = p;
  __syncthreads();
  float h = 0.f;
  for (int j = 0; j < seg; j++)
    h = fmaf(lp[j * 32 + dn], h, ls[j * 32 + dn]);
#pragma unroll
  for (int i = 0; i < 8; i++){
    const size_t idx = sbase + (size_t)(seg * 8 + i) * 16384;
    H[idx] = h;
    h = fmaf(Pv[i], h, Sv[i]);
  }
}

// ---------------- scan3: lean scan with true init + y, C=64, len=32. Grid (64,4,2). [R10 body]
__global__ __launch_bounds__(256) void k_scan3(const float* __restrict__ x,
                                               const float* __restrict__ del,
                                               const float* __restrict__ xz,
                                               const float* __restrict__ alog,
                                               const float* __restrict__ te,
                                               const float* __restrict__ Dpar,
                                               const float* __restrict__ H,
                                               float* __restrict__ out){
  const int t = threadIdx.x;
  const int chunk = blockIdx.x, dgrp = blockIdx.y, b = blockIdx.z;
  const int d = dgrp * 256 + t;
  const int l0 = chunk * 32;
  float a2[16];
  {
    const float4* ap = reinterpret_cast<const float4*>(alog + (size_t)d * 16);
#pragma unroll
    for (int q = 0; q < 4; q++){
      const float4 v = ap[q];
      a2[q*4+0] = -__expf(v.x) * LOG2E; a2[q*4+1] = -__expf(v.y) * LOG2E;
      a2[q*4+2] = -__expf(v.z) * LOG2E; a2[q*4+3] = -__expf(v.w) * LOG2E;
    }
  }
  bool uni = true;
#pragma unroll
  for (int n = 1; n < 16; n++) uni = uni && (a2[n] == a2[0]);
  const float sgv = 1.f / (1.f + __expf(-te[d]));
  const float Dv = Dpar[d];
  const size_t xidx0 = (size_t)(b * 2048 + l0) * 1024 + d;
  const float* xzb = xz + (size_t)(b * 2048 + l0) * 96;
  const size_t hbase = ((size_t)((b * 64 + chunk) * 1024 + d)) * 16;
  if (uni){
    const float a2u = a2[0];
    v2f h2[8];
    {
      const float4* hp = reinterpret_cast<const float4*>(H + hbase);
      float4* hd = reinterpret_cast<float4*>(h2);
#pragma unroll
      for (int q = 0; q < 4; q++) hd[q] = hp[q];
    }
    for (int ph = 0; ph < 2; ++ph){
      const size_t xidx = xidx0 + (size_t)ph * 16 * 1024;
      float dl[16], xd[16];
#pragma unroll
      for (int li = 0; li < 16; ++li){
        dl[li] = del[xidx + (size_t)li * 1024];
        xd[li] = x[xidx + (size_t)li * 1024] * sgv;
      }
#pragma unroll 4
      for (int li = 0; li < 16; ++li){
        const float duv = dl[li] * xd[li];
        const float tt = fexp2(dl[li] * a2u);
        const v2f tt2 = {tt, tt}, du2 = {duv, duv};
        const v2f* brow = reinterpret_cast<const v2f*>(xzb + (ph * 16 + li) * 96 + 64);
        const v2f* crow = reinterpret_cast<const v2f*>(xzb + (ph * 16 + li) * 96 + 80);
        v2f yv = {0.f, 0.f};
#pragma unroll
        for (int q = 0; q < 8; q++){
          h2[q] = h2[q] * tt2 + brow[q] * du2;
          yv = yv + h2[q] * crow[q];
        }
        out[xidx + (size_t)li * 1024] = fmaf(xd[li], Dv, yv.x + yv.y);
      }
    }
  } else {
    float h[16];
    {
      const float4* hp = reinterpret_cast<const float4*>(H + hbase);
#pragma unroll
      for (int q = 0; q < 4; q++){
        const float4 v = hp[q];
        h[q*4] = v.x; h[q*4+1] = v.y; h[q*4+2] = v.z; h[q*4+3] = v.w;
      }
    }
    for (int li = 0; li < 32; ++li){
      const float dv = del[xidx0 + (size_t)li * 1024];
      const float xdv = x[xidx0 + (size_t)li * 1024] * sgv;
      const float duv = dv * xdv;
      const float* brow = xzb + li * 96 + 64;
      float y = 0.f;
#pragma unroll
      for (int n = 0; n < 16; n++){
        const float tt = fexp2(dv * a2[n]);
        h[n] = fmaf(tt, h[n], duv * brow[n]);
        y = fmaf(h[n], brow[16 + n], y);
      }
      out[xidx0 + (size_t)li * 1024] = fmaf(xdv, Dv, y);
    }
  }
}

extern "C" void kernel_launch(void* const* d_in, const int* in_sizes, int n_in,
                              void* d_out, int out_size, void* d_ws, size_t ws_size,
                              hipStream_t stream){
  const float* x    = (const float*)d_in[0];
  const float* Alog = (const float*)d_in[1];
  const float* xpw  = (const float*)d_in[2];
  const float* dtw  = (const float*)d_in[3];
  const float* dtb  = (const float*)d_in[4];
  const float* Dpar = (const float*)d_in[5];
  const float* te   = (const float*)d_in[6];
  float* out = (float*)d_out;
  char* ws = (char*)d_ws;

  float* w2T  = (float*)(ws);             // 393216
  float* xz   = (float*)(ws + 393216);    // 1572864
  float* del  = (float*)(ws + 1966080);   // 16777216
  float* xzp  = (float*)(ws + 18743296);  // 12582912 (8 partials)
  float* S    = (float*)(ws + 31326208);  // 8388608
  float* P    = (float*)(ws + 39714816);  // 8388608
  float* Hst  = (float*)(ws + 48103424);  // 8388608 -> ends 56492032

  hipLaunchKernelGGL(k_prep,   dim3(96),        dim3(256), 0, stream, xpw, te, w2T);
  hipLaunchKernelGGL(k_xz,     dim3(16, 3, 8),  dim3(256), 0, stream, x, w2T, xzp);
  hipLaunchKernelGGL(k_reduce, dim3(384),       dim3(256), 0, stream, (const float4*)xzp, (float4*)xz);
  hipLaunchKernelGGL(k_scan1,  dim3(64, 4, 2),  dim3(256), 0, stream, x, xz, dtw, dtb, Alog, te, del, S, P);
  hipLaunchKernelGGL(k_scan2,  dim3(1024),      dim3(256), 0, stream, S, P, Hst);
  hipLaunchKernelGGL(k_scan3,  dim3(64, 4, 2),  dim3(256), 0, stream, x, del, xz, Alog, te, Dpar, Hst, out);
}

// Round 12
// 161.457 us; speedup vs baseline: 1.0312x; 1.0312x over previous
//
#include <hip/hip_runtime.h>
#include <math.h>

// SelectiveSSMBlock: B=2, L=2048, D=1024, N=16, R=64, fp32.
// R12 (final): exact restore of the R7 champion (161.2 us, passed).
// Plateau evidence R5-R11: 163.7/163.0/161.2/163.1/166.5 across structural
// variations — owned work is at its latency/overhead floor; largest measured
// dispatch is the harness ws-poison fill (268 MB @ ~78% HBM peak).

#define LOG2E 1.44269504088896340736f
typedef float v2f __attribute__((ext_vector_type(2)));

__device__ __forceinline__ float fexp2(float v){
#if defined(__has_builtin)
#if __has_builtin(__builtin_amdgcn_exp2f)
  return __builtin_amdgcn_exp2f(v);
#else
  return exp2f(v);
#endif
#else
  return exp2f(v);
#endif
}

__device__ __forceinline__ float fsoftplus(float v){
  return fmaxf(v, 0.f) + __logf(1.f + __expf(-fabsf(v)));
}

// ---------------- prep (R7)
__global__ __launch_bounds__(256) void k_prep(const float* __restrict__ xpw,
                                              const float* __restrict__ dtw,
                                              const float* __restrict__ alog,
                                              const float* __restrict__ te,
                                              float* __restrict__ w2T,
                                              float* __restrict__ dtwT,
                                              float* __restrict__ A2,
                                              float* __restrict__ sg){
  __shared__ float sm[32 * 33];
  const int bid = blockIdx.x, t = threadIdx.x;
  const int lane = t & 31, srow = t >> 5;
  if (bid < 96){
    const int kt = bid / 3, ct = bid - kt * 3;
#pragma unroll
    for (int r = 0; r < 4; r++){
      const int cr = srow * 4 + r;
      sm[cr * 33 + lane] = xpw[(size_t)(ct * 32 + cr) * 1024 + kt * 32 + lane];
    }
    __syncthreads();
#pragma unroll
    for (int r = 0; r < 4; r++){
      const int kr = srow * 4 + r;
      const int kg = kt * 32 + kr;
      const float s = 1.f / (1.f + __expf(-te[kg]));
      w2T[(size_t)kg * 96 + ct * 32 + lane] = sm[lane * 33 + kr] * s;
    }
  } else if (bid < 160){
    const int idx = bid - 96, dti = idx >> 1, kt2 = idx & 1;
#pragma unroll
    for (int r = 0; r < 4; r++){
      const int cr = srow * 4 + r;
      sm[cr * 33 + lane] = dtw[(size_t)(dti * 32 + cr) * 64 + kt2 * 32 + lane];
    }
    __syncthreads();
#pragma unroll
    for (int r = 0; r < 4; r++){
      const int kr = srow * 4 + r;
      dtwT[(size_t)(kt2 * 32 + kr) * 1024 + dti * 32 + lane] = sm[lane * 33 + kr];
    }
  } else if (bid < 176){
    const int j = (bid - 160) * 1024 + t;
#pragma unroll
    for (int i = 0; i < 4; i++)
      A2[j + i * 256] = -__expf(alog[j + i * 256]) * LOG2E;
  } else {
#pragma unroll
    for (int i = 0; i < 4; i++){
      const int m = i * 256 + t;
      sg[m] = 1.f / (1.f + __expf(-te[m]));
    }
  }
}

// ---------------- xz partial GEMM, K-split 8 (KC=128). Grid (16,3,8)=384.
__global__ __launch_bounds__(256) void k_xz(const float* __restrict__ x,
                                            const float* __restrict__ w2T,
                                            float* __restrict__ xzp){
  __shared__ float xT[32 * 257];
  const int t = threadIdx.x;
  const int row0 = blockIdx.x * 256;
  const int c0 = blockIdx.y * 32;
  const int kbase = blockIdx.z * 128;
  v2f acc[16];
#pragma unroll
  for (int c = 0; c < 16; c++) acc[c] = (v2f){0.f, 0.f};
  const int kq = t & 7, rsub = t >> 3;
  for (int kt = 0; kt < 4; ++kt){
    const int k0 = kbase + kt * 32;
    __syncthreads();
#pragma unroll
    for (int p = 0; p < 8; p++){
      const int r = p * 32 + rsub;
      const float4 v = *reinterpret_cast<const float4*>(&x[(size_t)(row0 + r) * 1024 + k0 + kq * 4]);
      xT[(kq * 4 + 0) * 257 + r] = v.x;
      xT[(kq * 4 + 1) * 257 + r] = v.y;
      xT[(kq * 4 + 2) * 257 + r] = v.z;
      xT[(kq * 4 + 3) * 257 + r] = v.w;
    }
    __syncthreads();
#pragma unroll 4
    for (int kk = 0; kk < 32; ++kk){
      const float xv = xT[kk * 257 + t];
      const v2f xv2 = {xv, xv};
      const v2f* wr = reinterpret_cast<const v2f*>(&w2T[(size_t)(k0 + kk) * 96 + c0]);
#pragma unroll
      for (int c = 0; c < 16; c++) acc[c] = acc[c] + xv2 * wr[c];
    }
  }
  float4* o = reinterpret_cast<float4*>(xzp + ((size_t)blockIdx.z * 4096 + row0 + t) * 96 + c0);
  const float4* av = reinterpret_cast<const float4*>(acc);
#pragma unroll
  for (int q = 0; q < 8; q++) o[q] = av[q];
}

// ---------------- reduce 8 partials -> xz
__global__ __launch_bounds__(256) void k_reduce(const float4* __restrict__ p,
                                                float4* __restrict__ xz){
  const int i = blockIdx.x * 256 + threadIdx.x;
  float4 r = p[i];
#pragma unroll
  for (int s = 1; s < 8; s++){
    const float4 a = p[(size_t)s * 98304 + i];
    r.x += a.x; r.y += a.y; r.z += a.z; r.w += a.w;
  }
  xz[i] = r;
}

// ---------------- delta = softplus(xz[:, :64] @ dtwT + dtb). Grid (256,4).
__global__ __launch_bounds__(256) void k_delta(const float* __restrict__ xz,
                                               const float* __restrict__ dtwT,
                                               const float* __restrict__ dtb,
                                               float* __restrict__ del){
  const int t = threadIdx.x;
  const int r0 = blockIdx.x * 16;
  const int d = blockIdx.y * 256 + t;
  v2f wv[32];
#pragma unroll
  for (int k2 = 0; k2 < 32; k2++){
    wv[k2].x = dtwT[(size_t)(2 * k2) * 1024 + d];
    wv[k2].y = dtwT[(size_t)(2 * k2 + 1) * 1024 + d];
  }
  const float dtbv = dtb[d];
  const float* xzb = xz + (size_t)r0 * 96;
#pragma unroll 4
  for (int li = 0; li < 16; ++li){
    v2f acc = {dtbv, 0.f};
    const v2f* dp = reinterpret_cast<const v2f*>(xzb + li * 96);  // uniform -> s_load
#pragma unroll
    for (int k2 = 0; k2 < 32; k2++) acc = acc + dp[k2] * wv[k2];
    del[(size_t)(r0 + li) * 1024 + d] = fsoftplus(acc.x + acc.y);
  }
}

// ---------------- scan1: lean local scan, C=64, len=32 (two 16-step phases).
__global__ __launch_bounds__(256) void k_scan1(const float* __restrict__ x,
                                               const float* __restrict__ del,
                                               const float* __restrict__ xz,
                                               const float* __restrict__ A2,
                                               const float* __restrict__ sg,
                                               float* __restrict__ S,
                                               float* __restrict__ P){
  const int t = threadIdx.x;
  const int chunk = blockIdx.x, dgrp = blockIdx.y, b = blockIdx.z;
  const int d = dgrp * 256 + t;
  const int l0 = chunk * 32;
  float a2[16];
  {
    const float4* ap = reinterpret_cast<const float4*>(A2 + (size_t)d * 16);
#pragma unroll
    for (int q = 0; q < 4; q++){
      const float4 v = ap[q];
      a2[q*4] = v.x; a2[q*4+1] = v.y; a2[q*4+2] = v.z; a2[q*4+3] = v.w;
    }
  }
  bool uni = true;
#pragma unroll
  for (int n = 1; n < 16; n++) uni = uni && (a2[n] == a2[0]);
  const float sgv = sg[d];
  const size_t xidx0 = (size_t)(b * 2048 + l0) * 1024 + d;
  const float* xzb = xz + (size_t)(b * 2048 + l0) * 96;
  const size_t base = ((size_t)((b * 64 + chunk) * 1024 + d)) * 16;
  if (uni){
    const float a2u = a2[0];
    v2f h2[8];
#pragma unroll
    for (int q = 0; q < 8; q++) h2[q] = (v2f){0.f, 0.f};
    float sumd = 0.f;
    for (int ph = 0; ph < 2; ++ph){
      const size_t xidx = xidx0 + (size_t)ph * 16 * 1024;
      float dl[16], du[16];
#pragma unroll
      for (int li = 0; li < 16; ++li){
        dl[li] = del[xidx + (size_t)li * 1024];
        du[li] = dl[li] * x[xidx + (size_t)li * 1024] * sgv;
      }
#pragma unroll 4
      for (int li = 0; li < 16; ++li){
        sumd += dl[li];
        const float tt = fexp2(dl[li] * a2u);
        const v2f tt2 = {tt, tt}, du2 = {du[li], du[li]};
        const v2f* brow = reinterpret_cast<const v2f*>(xzb + (ph * 16 + li) * 96 + 64);
#pragma unroll
        for (int q = 0; q < 8; q++) h2[q] = h2[q] * tt2 + brow[q] * du2;
      }
    }
    const float Ppu = fexp2(a2u * sumd);
    const float4* hv = reinterpret_cast<const float4*>(h2);
#pragma unroll
    for (int q = 0; q < 4; q++)
      *reinterpret_cast<float4*>(&S[base + q * 4]) = hv[q];
    const float4 pv = {Ppu, Ppu, Ppu, Ppu};
#pragma unroll
    for (int q = 0; q < 4; q++)
      *reinterpret_cast<float4*>(&P[base + q * 4]) = pv;
  } else {
    float h[16], Pp[16];
#pragma unroll
    for (int n = 0; n < 16; n++){ h[n] = 0.f; Pp[n] = 1.f; }
    for (int li = 0; li < 32; ++li){
      const float dv = del[xidx0 + (size_t)li * 1024];
      const float duv = dv * x[xidx0 + (size_t)li * 1024] * sgv;
      const float* brow = xzb + li * 96 + 64;
#pragma unroll
      for (int n = 0; n < 16; n++){
        const float tt = fexp2(dv * a2[n]);
        h[n] = fmaf(tt, h[n], duv * brow[n]);
        Pp[n] *= tt;
      }
    }
#pragma unroll
    for (int q = 0; q < 4; q++){
      float4 v; v.x = h[q*4]; v.y = h[q*4+1]; v.z = h[q*4+2]; v.w = h[q*4+3];
      *reinterpret_cast<float4*>(&S[base + q * 4]) = v;
      float4 u; u.x = Pp[q*4]; u.y = Pp[q*4+1]; u.z = Pp[q*4+2]; u.w = Pp[q*4+3];
      *reinterpret_cast<float4*>(&P[base + q * 4]) = u;
    }
  }
}

// ---------------- scan2: single-walk segmented combine, C=64. Grid 1024 x 256.
__global__ __launch_bounds__(256) void k_scan2(const float* __restrict__ S,
                                               const float* __restrict__ P,
                                               float* __restrict__ H){
  __shared__ float ls[256], lp[256];
  const int t = threadIdx.x;
  const int dn = t & 31, seg = t >> 5;
  const int n = dn & 15, dloc = dn >> 4;
  const int bid = blockIdx.x;
  const int b = bid >> 9, dpair = bid & 511;
  const int d = dpair * 2 + dloc;
  const size_t sbase = ((size_t)(b * 64) * 1024 + d) * 16 + n;
  float Sv[8], Pv[8];
  float s = 0.f, p = 1.f;
#pragma unroll
  for (int i = 0; i < 8; i++){
    const size_t idx = sbase + (size_t)(seg * 8 + i) * 16384;
    Sv[i] = S[idx]; Pv[i] = P[idx];
    s = fmaf(Pv[i], s, Sv[i]);
    p *= Pv[i];
  }
  ls[t] = s; lp[t] = p;
  __syncthreads();
  float h = 0.f;
  for (int j = 0; j < seg; j++)
    h = fmaf(lp[j * 32 + dn], h, ls[j * 32 + dn]);
#pragma unroll
  for (int i = 0; i < 8; i++){
    const size_t idx = sbase + (size_t)(seg * 8 + i) * 16384;
    H[idx] = h;
    h = fmaf(Pv[i], h, Sv[i]);
  }
}

// ---------------- scan3: lean scan with true init + y, C=64, len=32.
__global__ __launch_bounds__(256) void k_scan3(const float* __restrict__ x,
                                               const float* __restrict__ del,
                                               const float* __restrict__ xz,
                                               const float* __restrict__ A2,
                                               const float* __restrict__ sg,
                                               const float* __restrict__ Dpar,
                                               const float* __restrict__ H,
                                               float* __restrict__ out){
  const int t = threadIdx.x;
  const int chunk = blockIdx.x, dgrp = blockIdx.y, b = blockIdx.z;
  const int d = dgrp * 256 + t;
  const int l0 = chunk * 32;
  float a2[16];
  {
    const float4* ap = reinterpret_cast<const float4*>(A2 + (size_t)d * 16);
#pragma unroll
    for (int q = 0; q < 4; q++){
      const float4 v = ap[q];
      a2[q*4] = v.x; a2[q*4+1] = v.y; a2[q*4+2] = v.z; a2[q*4+3] = v.w;
    }
  }
  bool uni = true;
#pragma unroll
  for (int n = 1; n < 16; n++) uni = uni && (a2[n] == a2[0]);
  const float sgv = sg[d], Dv = Dpar[d];
  const size_t xidx0 = (size_t)(b * 2048 + l0) * 1024 + d;
  const float* xzb = xz + (size_t)(b * 2048 + l0) * 96;
  const size_t hbase = ((size_t)((b * 64 + chunk) * 1024 + d)) * 16;
  if (uni){
    const float a2u = a2[0];
    v2f h2[8];
    {
      const float4* hp = reinterpret_cast<const float4*>(H + hbase);
      float4* hd = reinterpret_cast<float4*>(h2);
#pragma unroll
      for (int q = 0; q < 4; q++) hd[q] = hp[q];
    }
    for (int ph = 0; ph < 2; ++ph){
      const size_t xidx = xidx0 + (size_t)ph * 16 * 1024;
      float dl[16], xd[16];
#pragma unroll
      for (int li = 0; li < 16; ++li){
        dl[li] = del[xidx + (size_t)li * 1024];
        xd[li] = x[xidx + (size_t)li * 1024] * sgv;
      }
#pragma unroll 4
      for (int li = 0; li < 16; ++li){
        const float duv = dl[li] * xd[li];
        const float tt = fexp2(dl[li] * a2u);
        const v2f tt2 = {tt, tt}, du2 = {duv, duv};
        const v2f* brow = reinterpret_cast<const v2f*>(xzb + (ph * 16 + li) * 96 + 64);
        const v2f* crow = reinterpret_cast<const v2f*>(xzb + (ph * 16 + li) * 96 + 80);
        v2f yv = {0.f, 0.f};
#pragma unroll
        for (int q = 0; q < 8; q++){
          h2[q] = h2[q] * tt2 + brow[q] * du2;
          yv = yv + h2[q] * crow[q];
        }
        out[xidx + (size_t)li * 1024] = fmaf(xd[li], Dv, yv.x + yv.y);
      }
    }
  } else {
    float h[16];
    {
      const float4* hp = reinterpret_cast<const float4*>(H + hbase);
#pragma unroll
      for (int q = 0; q < 4; q++){
        const float4 v = hp[q];
        h[q*4] = v.x; h[q*4+1] = v.y; h[q*4+2] = v.z; h[q*4+3] = v.w;
      }
    }
    for (int li = 0; li < 32; ++li){
      const float dv = del[xidx0 + (size_t)li * 1024];
      const float xdv = x[xidx0 + (size_t)li * 1024] * sgv;
      const float duv = dv * xdv;
      const float* brow = xzb + li * 96 + 64;
      float y = 0.f;
#pragma unroll
      for (int n = 0; n < 16; n++){
        const float tt = fexp2(dv * a2[n]);
        h[n] = fmaf(tt, h[n], duv * brow[n]);
        y = fmaf(h[n], brow[16 + n], y);
      }
      out[xidx0 + (size_t)li * 1024] = fmaf(xdv, Dv, y);
    }
  }
}

extern "C" void kernel_launch(void* const* d_in, const int* in_sizes, int n_in,
                              void* d_out, int out_size, void* d_ws, size_t ws_size,
                              hipStream_t stream){
  const float* x    = (const float*)d_in[0];
  const float* Alog = (const float*)d_in[1];
  const float* xpw  = (const float*)d_in[2];
  const float* dtw  = (const float*)d_in[3];
  const float* dtb  = (const float*)d_in[4];
  const float* Dpar = (const float*)d_in[5];
  const float* te   = (const float*)d_in[6];
  float* out = (float*)d_out;
  char* ws = (char*)d_ws;

  float* w2T  = (float*)(ws);             // 393216
  float* A2   = (float*)(ws + 393216);    // 65536
  float* sg   = (float*)(ws + 458752);    // 4096
  float* dtwT = (float*)(ws + 462848);    // 262144
  float* xz   = (float*)(ws + 724992);    // 1572864
  float* del  = (float*)(ws + 2297856);   // 16777216
  float* xzp  = (float*)(ws + 19075072);  // 12582912 (8 partials)
  float* S    = (float*)(ws + 31657984);  // 8388608
  float* P    = (float*)(ws + 40046592);  // 8388608
  float* Hst  = (float*)(ws + 48435200);  // 8388608 -> ends 56823808

  hipLaunchKernelGGL(k_prep,   dim3(177),        dim3(256), 0, stream, xpw, dtw, Alog, te, w2T, dtwT, A2, sg);
  hipLaunchKernelGGL(k_xz,     dim3(16, 3, 8),   dim3(256), 0, stream, x, w2T, xzp);
  hipLaunchKernelGGL(k_reduce, dim3(384),        dim3(256), 0, stream, (const float4*)xzp, (float4*)xz);
  hipLaunchKernelGGL(k_delta,  dim3(256, 4),     dim3(256), 0, stream, xz, dtwT, dtb, del);
  hipLaunchKernelGGL(k_scan1,  dim3(64, 4, 2),   dim3(256), 0, stream, x, del, xz, A2, sg, S, P);
  hipLaunchKernelGGL(k_scan2,  dim3(1024),       dim3(256), 0, stream, S, P, Hst);
  hipLaunchKernelGGL(k_scan3,  dim3(64, 4, 2),   dim3(256), 0, stream, x, del, xz, A2, sg, Dpar, Hst, out);
}